// Round 8
// baseline (26.039 us; speedup 1.0000x reference)
//
#include <hip/hip_runtime.h>
#include <math.h>

#define HW     76800
#define NBATCH 8
#define NB     256
#define NEDGE  257
#define ELEMS  12
#define XBLKS  25                      // HW / (256*ELEMS) exactly
#define FINF 3.402823466e+38f

// ws layout (memset 0 over [0,8704) each call):
//   [0,384)    double sums[48]   6 per batch: {cnt,ssq,sd,sd2,dir2,dir1}
//   [384,420)  uint tickets[9]   8 per-batch + 1 global
//   [512,8704) uint gD[8][256]   complement-space bracket mins (0 == +inf)
//
// All cross-block traffic is ATOMIC (device coherence point); ordering before
// each ticket needs only s_waitcnt vmcnt(0), NOT __threadfence() (agent fence
// on gfx950 = L2 writeback storm — measured +20us in round 4).

__device__ __forceinline__ unsigned int nzb(unsigned int w) {
  return ((w & 0xFFu) != 0u) + (((w >> 8) & 0xFFu) != 0u) +
         (((w >> 16) & 0xFFu) != 0u) + ((w >> 24) != 0u);
}

__global__ __launch_bounds__(256) void k_all(
    const float* __restrict__ p, const float* __restrict__ t,
    const void* __restrict__ mask, const float* __restrict__ edges,
    double* __restrict__ sums, unsigned int* __restrict__ tickets,
    unsigned int* __restrict__ gD, float* __restrict__ out) {
  __shared__ float c_lds[NB + 1];        // sorted centers; +inf sentinel at [256]
  __shared__ float2 lut[NB];             // {c[k], k}: largest k with c[k] <= q/256
  __shared__ unsigned int d_lds[NB + 2]; // center j at [j+1]; 0,257 = dummy sinks
  __shared__ float df[NB];               // combiner: decoded bracket mins
  __shared__ float shred[4][5];
  __shared__ unsigned int sh_u[4];
  __shared__ double fin[48];
  __shared__ unsigned int comb;

  const int tid = threadIdx.x, lane = tid & 63, wid = tid >> 6;
  const int b = blockIdx.y;
  const int ebase = b * HW + blockIdx.x * (NB * ELEMS) + tid * ELEMS;

  // ---- 1. issue the long-latency loads FIRST (they complete under the sort) --
  float4 p4[3], t4[3];
  {
    const float4* pp = (const float4*)(p + ebase);
    const float4* tt = (const float4*)(t + ebase);
    p4[0] = pp[0]; p4[1] = pp[1]; p4[2] = pp[2];
    t4[0] = tt[0]; t4[1] = tt[1]; t4[2] = tt[2];
  }
  const uint4 raw = ((const uint4*)mask)[tid];  // first 4KB, same in every block
  const float e0 = edges[b * NEDGE + tid];
  const float e1 = edges[b * NEDGE + tid + 1];

  // ---- 2. mask dtype detect (bool bytes ~2048/4096 nonzero; int32 ~512) ----
  unsigned int cnz = nzb(raw.x) + nzb(raw.y) + nzb(raw.z) + nzb(raw.w);
#pragma unroll
  for (int o = 32; o > 0; o >>= 1) cnz += __shfl_down(cnz, o, 64);
  if (lane == 0) sh_u[wid] = cnz;
  __syncthreads();
  const bool bytemode = (sh_u[0] + sh_u[1] + sh_u[2] + sh_u[3]) > 1024u;

  // issue mask loads now (overlap with sort below)
  int me[ELEMS];
  if (bytemode) {
    const unsigned int* mp = (const unsigned int*)((const unsigned char*)mask + ebase);
    unsigned int w[3] = {mp[0], mp[1], mp[2]};
#pragma unroll
    for (int e = 0; e < ELEMS; ++e) me[e] = (w[e >> 2] >> ((e & 3) * 8)) & 0xFFu;
  } else {
    const int4* mp = (const int4*)((const int*)mask + ebase);
#pragma unroll
    for (int q = 0; q < 3; ++q) {
      int4 m4 = mp[q];
      me[q * 4 + 0] = m4.x; me[q * 4 + 1] = m4.y; me[q * 4 + 2] = m4.z; me[q * 4 + 3] = m4.w;
    }
  }

  // ---- 3. bitonic sort of this batch's 256 centers (shfl; LDS only j>=64) ----
  float v = 0.5f * (e0 + e1);
  for (int k = 2; k <= NB; k <<= 1) {
    for (int j = k >> 1; j > 0; j >>= 1) {
      float partner;
      if (j < 64) {
        partner = __shfl_xor(v, j, 64);
      } else {
        __syncthreads();
        c_lds[tid] = v;
        __syncthreads();
        partner = c_lds[tid ^ j];
      }
      const bool up = ((tid & k) == 0);
      const bool low = ((tid & j) == 0);
      v = (low == up) ? fminf(v, partner) : fmaxf(v, partner);
    }
  }
  __syncthreads();
  c_lds[tid] = v;
  if (tid == 0) c_lds[NB] = FINF;
  lut[tid] = make_float2(-FINF, __int_as_float(-1));
  d_lds[tid] = 0u;                       // complement space: 0 == +inf
  if (tid < 2) d_lds[NB + tid] = 0u;
  __syncthreads();

  // ---- 4. LUT by range-scatter: thread k covers q in [ceil(256c_k), ceil(256c_{k+1})-1]
  {
    const float cn1 = c_lds[tid + 1];
    int lo = (int)ceilf(v * 256.0f);  lo = (lo < 0) ? 0 : lo;
    int hi = (tid == 255) ? 255 : ((int)ceilf(cn1 * 256.0f) - 1);
    hi = (hi > 255) ? 255 : hi;
    const float2 entry = make_float2(v, __int_as_float(tid));
    for (int q = lo; q <= hi; ++q) lut[q] = entry;
  }
  __syncthreads();

  // ---- 5. masked reductions (loads arrived long ago) ----
  float pe[ELEMS], te[ELEMS];
#pragma unroll
  for (int q = 0; q < 3; ++q) {
    pe[q * 4 + 0] = p4[q].x; pe[q * 4 + 1] = p4[q].y; pe[q * 4 + 2] = p4[q].z; pe[q * 4 + 3] = p4[q].w;
    te[q * 4 + 0] = t4[q].x; te[q * 4 + 1] = t4[q].y; te[q * 4 + 2] = t4[q].z; te[q * 4 + 3] = t4[q].w;
  }
  int cnt = 0;
  float ssq = 0.f, sd = 0.f, sd2 = 0.f, dir2 = 0.f;
#pragma unroll
  for (int e = 0; e < ELEMS; ++e) {
    if (me[e]) {
      float diff = pe[e] - te[e];
      float d = logf(pe[e] + 1e-10f) - logf(te[e] + 1e-10f);
      cnt += 1;
      ssq += diff * diff;
      sd  += d;
      sd2 += d * d;
    }
  }

  // ---- 6. chamfer: LUT start + short forward scan ----
#pragma unroll
  for (int e = 0; e < ELEMS; ++e) {
    const float ti = te[e];
    int q = (int)(ti * 256.0f);
    q = (q < 0) ? 0 : ((q > 255) ? 255 : q);
    float2 lu = lut[q];
    float c0 = lu.x;
    int k = __float_as_int(lu.y);
    float cn = c_lds[k + 1];
    while (cn <= ti) { ++k; c0 = cn; cn = c_lds[k + 1]; }  // c_lds[256]=inf stops
    float dl = ti - c0;   // +inf when k==-1 (c0 = -inf)
    float dr = cn - ti;   // +inf when k==255
    atomicMax(&d_lds[k + 1], ~__float_as_uint(dl));  // k==-1 -> dummy slot 0
    atomicMax(&d_lds[k + 2], ~__float_as_uint(dr));  // k==255 -> dummy slot 257
    float dm = fminf(dl, dr);
    dir2 += dm * dm;
  }

  __syncthreads();
  {
    unsigned int dv = d_lds[tid + 1];
    if (dv) atomicMax(&gD[b * NB + tid], dv);
  }

  // ---- 7. block reduction -> per-batch f64 atomics ----
  float acc[5] = {(float)cnt, ssq, sd, sd2, dir2};
#pragma unroll
  for (int i = 0; i < 5; ++i) {
    float r = acc[i];
#pragma unroll
    for (int o = 32; o > 0; o >>= 1) r += __shfl_down(r, o, 64);
    if (lane == 0) shred[wid][i] = r;
  }
  __syncthreads();
  if (tid < 5) {
    atomicAdd(&sums[b * 6 + tid],
              (double)(shred[0][tid] + shred[1][tid] + shred[2][tid] + shred[3][tid]));
  }

  // ---- 8. per-batch ticket: last of 25 blocks combines this batch ----
  asm volatile("s_waitcnt vmcnt(0) lgkmcnt(0)" ::: "memory");
  __syncthreads();
  if (tid == 0)
    comb = (atomicAdd(&tickets[b], 1u) == (unsigned)(XBLKS - 1)) ? 1u : 0u;
  __syncthreads();
  if (comb == 0u) return;

  // ---- 9. combiner: distance transform over this batch's centers ----
  {
    unsigned int s = atomicOr(&gD[b * NB + tid], 0u);
    df[tid] = s ? __uint_as_float(~s) : FINF;
  }
  __syncthreads();
  if (tid < 64) {
    float c[4], D[4];
#pragma unroll
    for (int i = 0; i < 4; ++i) {
      c[i] = c_lds[tid * 4 + i];
      D[i] = df[tid * 4 + i];
    }
    float pa[4];
    pa[0] = D[0] - c[0];
    pa[1] = fminf(pa[0], D[1] - c[1]);
    pa[2] = fminf(pa[1], D[2] - c[2]);
    pa[3] = fminf(pa[2], D[3] - c[3]);
    float s1 = pa[3];
#pragma unroll
    for (int off = 1; off < 64; off <<= 1) {
      float u = __shfl_up(s1, off, 64);
      if (tid >= off) s1 = fminf(s1, u);
    }
    float exL = __shfl_up(s1, 1, 64);
    if (tid == 0) exL = FINF;

    float sb[4];
    sb[3] = D[3] + c[3];
    sb[2] = fminf(sb[3], D[2] + c[2]);
    sb[1] = fminf(sb[2], D[1] + c[1]);
    sb[0] = fminf(sb[1], D[0] + c[0]);
    float s2 = sb[0];
#pragma unroll
    for (int off = 1; off < 64; off <<= 1) {
      float u = __shfl_down(s2, off, 64);
      if (tid + off < 64) s2 = fminf(s2, u);
    }
    float exR = __shfl_down(s2, 1, 64);
    if (tid == 63) exR = FINF;

    double dir1 = 0.0;
#pragma unroll
    for (int i = 0; i < 4; ++i) {
      float pref = fminf(exL, pa[i]);
      float suf  = fminf(exR, sb[i]);
      float dist = fminf(pref + c[i], suf - c[i]);
      dir1 += (double)dist * (double)dist;
    }
#pragma unroll
    for (int o = 32; o > 0; o >>= 1) dir1 += __shfl_down(dir1, o, 64);
    if (tid == 0) atomicAdd(&sums[b * 6 + 5], dir1);
  }

  // ---- 10. global ticket: last of 8 combiners finalizes ----
  asm volatile("s_waitcnt vmcnt(0) lgkmcnt(0)" ::: "memory");
  __syncthreads();
  if (tid == 0)
    comb = (atomicAdd(&tickets[8], 1u) == (unsigned)(NBATCH - 1)) ? 1u : 0u;
  __syncthreads();
  if (comb == 0u) return;

  if (tid < 48) fin[tid] = atomicAdd(&sums[tid], 0.0);
  __syncthreads();
  if (tid == 0) {
    double cnt_ = 0, ssq_ = 0, sd_ = 0, sd2_ = 0, d2_ = 0, d1_ = 0;
#pragma unroll
    for (int bb = 0; bb < NBATCH; ++bb) {
      cnt_ += fin[bb * 6 + 0]; ssq_ += fin[bb * 6 + 1];
      sd_  += fin[bb * 6 + 2]; sd2_ += fin[bb * 6 + 3];
      d2_  += fin[bb * 6 + 4]; d1_  += fin[bb * 6 + 5];
    }
    double l2 = sqrt(ssq_ / cnt_);
    double dm = sd_ / cnt_, d2m = sd2_ / cnt_;
    double silog = 10.0 * sqrt(d2m - 0.85 * dm * dm);
    double chamfer = (d1_ + d2_) / (double)NBATCH;
    out[0] = (float)(l2 + silog + chamfer);
  }
}

extern "C" void kernel_launch(void* const* d_in, const int* in_sizes, int n_in,
                              void* d_out, int out_size, void* d_ws, size_t ws_size,
                              hipStream_t stream) {
  const float* pred  = (const float*)d_in[0];
  const float* targ  = (const float*)d_in[1];
  const float* edges = (const float*)d_in[2];
  const void*  mask  = d_in[3];

  char* ws = (char*)d_ws;
  double* sums          = (double*)ws;
  unsigned int* tickets = (unsigned int*)(ws + 384);
  unsigned int* gD      = (unsigned int*)(ws + 512);

  hipMemsetAsync(ws, 0, 8704, stream);
  k_all<<<dim3(XBLKS, NBATCH), NB, 0, stream>>>(pred, targ, mask, edges,
                                                sums, tickets, gD, (float*)d_out);
}

// Round 9
// 22.209 us; speedup vs baseline: 1.1724x; 1.1724x over previous
//
#include <hip/hip_runtime.h>
#include <math.h>

#define HW     76800
#define NBATCH 8
#define NB     256
#define NEDGE  257
#define ELEMS  12
#define XBLKS  25                      // HW / (256*ELEMS) exactly
#define MAIN_BLOCKS (XBLKS * NBATCH)   // 200 blocks <= 256 CUs: one generation
#define FINF 3.402823466e+38f

// ws layout (all (re)initialized by k_prep every call — no memset node):
//   [0,320)      double sums[40]   5 per batch: {cnt,ssq,sd,sd2,dir2}
//   [320,324)    uint ticket
//   [324,328)    uint flag          1 = mask is bytes, 0 = int32
//   [512,8704)   uint gD[8][256]    complement-space bracket mins (0 == +inf)
//   [8704,16896) float cs[8][256]   sorted centers
//
// Cross-block traffic inside k_main is ATOMIC (device coherence point);
// ordering before the ticket needs only s_waitcnt vmcnt(0), NOT
// __threadfence() (agent fence = L2-writeback storm, +20us, round 4).
// k_prep->k_main data (cs, flag) crosses a dispatch boundary: plain loads ok.

__device__ __forceinline__ float wsum32(float v) {
#pragma unroll
  for (int o = 32; o > 0; o >>= 1) v += __shfl_down(v, o, 64);
  return v;
}

__device__ __forceinline__ unsigned int nzb(unsigned int w) {
  return ((w & 0xFFu) != 0u) + (((w >> 8) & 0xFFu) != 0u) +
         (((w >> 16) & 0xFFu) != 0u) + ((w >> 24) != 0u);
}

__global__ void __launch_bounds__(256) k_prep(
    const float* __restrict__ edges, const unsigned char* __restrict__ mask,
    double* __restrict__ sums, unsigned int* __restrict__ ticket,
    unsigned int* __restrict__ flag, unsigned int* __restrict__ gD,
    float* __restrict__ cs) {
  const int tid = threadIdx.x, b = blockIdx.x;
  if (b < NBATCH) {
    // bitonic sort of this batch's 256 centers (shfl stages; LDS only j>=64)
    __shared__ float s[NB];
    float v = 0.5f * (edges[b * NEDGE + tid] + edges[b * NEDGE + tid + 1]);
    for (int k = 2; k <= NB; k <<= 1) {
      for (int j = k >> 1; j > 0; j >>= 1) {
        float partner;
        if (j < 64) {
          partner = __shfl_xor(v, j, 64);
        } else {
          __syncthreads();
          s[tid] = v;
          __syncthreads();
          partner = s[tid ^ j];
        }
        const bool up = ((tid & k) == 0);
        const bool low = ((tid & j) == 0);
        v = (low == up) ? fminf(v, partner) : fmaxf(v, partner);
      }
    }
    cs[b * NB + tid] = v;
    gD[b * NB + tid] = 0u;             // complement space: 0 == +inf
  } else {
    // mask dtype detect from first 4KB: bool ~2048/4096 nonzero bytes, int32 ~512
    uint4 raw = ((const uint4*)mask)[tid];
    unsigned int c = nzb(raw.x) + nzb(raw.y) + nzb(raw.z) + nzb(raw.w);
#pragma unroll
    for (int o = 32; o > 0; o >>= 1) c += __shfl_down(c, o, 64);
    __shared__ unsigned int sh[4];
    if ((tid & 63) == 0) sh[tid >> 6] = c;
    __syncthreads();
    if (tid == 0) *flag = ((sh[0] + sh[1] + sh[2] + sh[3]) > 1024u) ? 1u : 0u;
    if (tid < 40) sums[tid] = 0.0;
    if (tid == 40) *ticket = 0u;
  }
}

__global__ void __launch_bounds__(256) k_main(
    const float* __restrict__ p, const float* __restrict__ t,
    const void* __restrict__ mask, const unsigned int* __restrict__ flag,
    const float* __restrict__ cs, double* __restrict__ sums,
    unsigned int* __restrict__ gD, unsigned int* __restrict__ ticket,
    float* __restrict__ out) {
  __shared__ float c_lds[NB + 1];        // +inf sentinel at [256]
  __shared__ float2 lut[NB];             // {c[k],k}: largest k with c[k] <= q/256
  __shared__ unsigned int d_lds[NB + 2]; // center j at [j+1]; 0,257 = dummy sinks
  __shared__ float shred[4][5];
  __shared__ double dpart[4];
  __shared__ double fin[40];
  __shared__ unsigned int last_flag;

  const int tid = threadIdx.x, lane = tid & 63, wid = tid >> 6;
  const int b = blockIdx.y;
  const int ebase = b * HW + blockIdx.x * (NB * ELEMS) + tid * ELEMS;

  // ---- issue loads: flag first (mask branch depends on it), then bulk ----
  const unsigned int fl = *flag;
  float4 p4[3], t4[3];
  {
    const float4* pp = (const float4*)(p + ebase);
    const float4* tt = (const float4*)(t + ebase);
    p4[0] = pp[0]; p4[1] = pp[1]; p4[2] = pp[2];
    t4[0] = tt[0]; t4[1] = tt[1]; t4[2] = tt[2];
  }
  int me[ELEMS];
  if (fl) {
    const unsigned int* mp = (const unsigned int*)((const unsigned char*)mask + ebase);
    unsigned int w[3] = {mp[0], mp[1], mp[2]};
#pragma unroll
    for (int e = 0; e < ELEMS; ++e) me[e] = (w[e >> 2] >> ((e & 3) * 8)) & 0xFFu;
  } else {
    const int4* mp = (const int4*)((const int*)mask + ebase);
#pragma unroll
    for (int q = 0; q < 3; ++q) {
      int4 m4 = mp[q];
      me[q * 4 + 0] = m4.x; me[q * 4 + 1] = m4.y; me[q * 4 + 2] = m4.z; me[q * 4 + 3] = m4.w;
    }
  }

  // ---- stage LDS (overlaps with the bulk loads above) ----
  c_lds[tid] = cs[b * NB + tid];
  lut[tid] = make_float2(-FINF, __int_as_float(-1));
  d_lds[tid] = 0u;
  if (tid < 2) d_lds[NB + tid] = 0u;
  if (tid == 0) c_lds[NB] = FINF;
  __syncthreads();

  // ---- LUT by range-scatter: thread k covers q in [ceil(256c_k), ceil(256c_{k+1})-1]
  {
    const float cv = c_lds[tid];
    const float cn1 = c_lds[tid + 1];
    int lo = (int)ceilf(cv * 256.0f);
    lo = (lo < 0) ? 0 : lo;
    int hi = (tid == 255) ? 255 : ((int)ceilf(cn1 * 256.0f) - 1);
    hi = (hi > 255) ? 255 : hi;
    const float2 entry = make_float2(cv, __int_as_float(tid));
    for (int q = lo; q <= hi; ++q) lut[q] = entry;
  }
  __syncthreads();

  // ---- masked reductions (f32 partials, int count) ----
  float pe[ELEMS], te[ELEMS];
#pragma unroll
  for (int q = 0; q < 3; ++q) {
    pe[q * 4 + 0] = p4[q].x; pe[q * 4 + 1] = p4[q].y; pe[q * 4 + 2] = p4[q].z; pe[q * 4 + 3] = p4[q].w;
    te[q * 4 + 0] = t4[q].x; te[q * 4 + 1] = t4[q].y; te[q * 4 + 2] = t4[q].z; te[q * 4 + 3] = t4[q].w;
  }
  int cnt = 0;
  float ssq = 0.f, sd = 0.f, sd2 = 0.f, dir2 = 0.f;
#pragma unroll
  for (int e = 0; e < ELEMS; ++e) {
    if (me[e]) {
      float diff = pe[e] - te[e];
      float d = logf(pe[e] + 1e-10f) - logf(te[e] + 1e-10f);
      cnt += 1;
      ssq += diff * diff;
      sd  += d;
      sd2 += d * d;
    }
  }

  // ---- chamfer: LUT start + short forward scan ----
#pragma unroll
  for (int e = 0; e < ELEMS; ++e) {
    const float ti = te[e];
    int q = (int)(ti * 256.0f);
    q = (q < 0) ? 0 : ((q > 255) ? 255 : q);
    float2 lu = lut[q];
    float c0 = lu.x;
    int k = __float_as_int(lu.y);
    float cn = c_lds[k + 1];
    while (cn <= ti) { ++k; c0 = cn; cn = c_lds[k + 1]; }  // c_lds[256]=inf stops
    float dl = ti - c0;   // +inf when k==-1 (c0 = -inf)
    float dr = cn - ti;   // +inf when k==255
    atomicMax(&d_lds[k + 1], ~__float_as_uint(dl));  // k==-1 -> dummy slot 0
    atomicMax(&d_lds[k + 2], ~__float_as_uint(dr));  // k==255 -> dummy slot 257
    float dm = fminf(dl, dr);
    dir2 += dm * dm;
  }

  __syncthreads();
  {
    unsigned int dv = d_lds[tid + 1];
    if (dv) atomicMax(&gD[b * NB + tid], dv);
  }

  // ---- block reduction: 5 f32 wave-sums -> per-batch f64 atomics ----
  float acc[5] = {(float)cnt, ssq, sd, sd2, dir2};
#pragma unroll
  for (int i = 0; i < 5; ++i) {
    float r = wsum32(acc[i]);
    if (lane == 0) shred[wid][i] = r;
  }
  __syncthreads();
  if (tid < 5) {
    atomicAdd(&sums[b * 5 + tid],
              (double)(shred[0][tid] + shred[1][tid] + shred[2][tid] + shred[3][tid]));
  }

  // ---- ticket: wait only for OWN atomics (no L2-writeback fence) ----
  asm volatile("s_waitcnt vmcnt(0) lgkmcnt(0)" ::: "memory");
  __syncthreads();
  if (tid == 0)
    last_flag = (atomicAdd(ticket, 1u) == (unsigned)(MAIN_BLOCKS - 1)) ? 1u : 0u;
  __syncthreads();
  if (last_flag == 0u) return;

  // ---- finalizer (last block): distance transform over all 8 batches ----
  if (tid < 40) fin[tid] = atomicAdd(&sums[tid], 0.0);

  double dir1 = 0.0;
#pragma unroll
  for (int r = 0; r < 2; ++r) {
    const int bb = wid + r * 4;
    float c[4], D[4];
#pragma unroll
    for (int i = 0; i < 4; ++i) {
      const int idx = bb * NB + lane * 4 + i;
      c[i] = cs[idx];                              // k_prep data: plain read ok
      unsigned int s = atomicOr(&gD[idx], 0u);     // intra-kernel data: atomic
      D[i] = s ? __uint_as_float(~s) : FINF;
    }

    float pa[4];
    pa[0] = D[0] - c[0];
    pa[1] = fminf(pa[0], D[1] - c[1]);
    pa[2] = fminf(pa[1], D[2] - c[2]);
    pa[3] = fminf(pa[2], D[3] - c[3]);
    float s1 = pa[3];
#pragma unroll
    for (int off = 1; off < 64; off <<= 1) {
      float u = __shfl_up(s1, off, 64);
      if (lane >= off) s1 = fminf(s1, u);
    }
    float exL = __shfl_up(s1, 1, 64);
    if (lane == 0) exL = FINF;

    float sb[4];
    sb[3] = D[3] + c[3];
    sb[2] = fminf(sb[3], D[2] + c[2]);
    sb[1] = fminf(sb[2], D[1] + c[1]);
    sb[0] = fminf(sb[1], D[0] + c[0]);
    float s2 = sb[0];
#pragma unroll
    for (int off = 1; off < 64; off <<= 1) {
      float u = __shfl_down(s2, off, 64);
      if (lane + off < 64) s2 = fminf(s2, u);
    }
    float exR = __shfl_down(s2, 1, 64);
    if (lane == 63) exR = FINF;

#pragma unroll
    for (int i = 0; i < 4; ++i) {
      float pref = fminf(exL, pa[i]);
      float suf  = fminf(exR, sb[i]);
      float dist = fminf(pref + c[i], suf - c[i]);
      dir1 += (double)dist * (double)dist;
    }
  }

#pragma unroll
  for (int o = 32; o > 0; o >>= 1) dir1 += __shfl_down(dir1, o, 64);
  if (lane == 0) dpart[wid] = dir1;
  __syncthreads();
  if (tid == 0) {
    double d1 = dpart[0] + dpart[1] + dpart[2] + dpart[3];
    double cnt_ = 0, ssq_ = 0, sd_ = 0, sd2_ = 0, d2_ = 0;
#pragma unroll
    for (int bb = 0; bb < NBATCH; ++bb) {
      cnt_ += fin[bb * 5 + 0]; ssq_ += fin[bb * 5 + 1];
      sd_  += fin[bb * 5 + 2]; sd2_ += fin[bb * 5 + 3];
      d2_  += fin[bb * 5 + 4];
    }
    double l2 = sqrt(ssq_ / cnt_);
    double dm = sd_ / cnt_, d2m = sd2_ / cnt_;
    double silog = 10.0 * sqrt(d2m - 0.85 * dm * dm);
    double chamfer = (d1 + d2_) / (double)NBATCH;
    out[0] = (float)(l2 + silog + chamfer);
  }
}

extern "C" void kernel_launch(void* const* d_in, const int* in_sizes, int n_in,
                              void* d_out, int out_size, void* d_ws, size_t ws_size,
                              hipStream_t stream) {
  const float* pred  = (const float*)d_in[0];
  const float* targ  = (const float*)d_in[1];
  const float* edges = (const float*)d_in[2];
  const void*  mask  = d_in[3];

  char* ws = (char*)d_ws;
  double* sums         = (double*)ws;
  unsigned int* ticket = (unsigned int*)(ws + 320);
  unsigned int* flag   = (unsigned int*)(ws + 324);
  unsigned int* gD     = (unsigned int*)(ws + 512);
  float* cs            = (float*)(ws + 8704);

  k_prep<<<NBATCH + 1, NB, 0, stream>>>(edges, (const unsigned char*)mask,
                                        sums, ticket, flag, gD, cs);
  k_main<<<dim3(XBLKS, NBATCH), NB, 0, stream>>>(pred, targ, mask, flag, cs,
                                                 sums, gD, ticket, (float*)d_out);
}